// Round 3
// baseline (52.034 us; speedup 1.0000x reference)
//
#include <hip/hip_runtime.h>
#include <hip/hip_bf16.h>

#define B_ 4
#define N_ 20000
#define D_ 128
#define E_ 100000
#define TILES_ 625      // 20000 / 32, exact
#define NBUCKET 16

typedef __attribute__((ext_vector_type(8))) short bf16x8;
typedef __attribute__((ext_vector_type(4))) float f32x4;

// ws layout (float units):
// [0]             flag (int: 1 = edges are int64)
// [256,8448)      gbuf: NBUCKET x (B_*D_) atomic buckets
// [8448,16640)    w7frag: 2048 x bf16x8 (32 KB), W7 in MFMA B-fragment order
// [16640,96640)   qi (B x N)
// [96640,176640)  qj (B x N)

// blocks 0..7: W7 -> fragment-order bf16. block 8: int64 detect. 9..40: zero gbuf.
__global__ __launch_bounds__(256) void k_prep(
    const float* __restrict__ W7, const unsigned* __restrict__ ew,
    int* __restrict__ flag, float* __restrict__ gbuf, bf16x8* __restrict__ w7f)
{
    const int bx = blockIdx.x, t = threadIdx.x;
    if (bx < 8) {
        int f = bx * 256 + t;                 // fragment id 0..2047
        int tt = f >> 8, s = (f >> 6) & 3, lane = f & 63;
        int kg = lane >> 4, rc = lane & 15;
        int col = tt * 16 + rc, k0 = s * 32 + kg * 8;
        union { bf16x8 v; __hip_bfloat16 h[8]; } pk;
        #pragma unroll
        for (int m = 0; m < 8; ++m)
            pk.h[m] = __float2bfloat16(W7[(k0 + m) * D_ + col]);
        w7f[f] = pk.v;
    } else if (bx == 8) {
        if (t < 64) {
            unsigned v = ew[2 * t + 1];       // high words if int64 (all zero)
            unsigned long long any = __ballot(v != 0u);
            if (t == 0) *flag = (any == 0ULL) ? 1 : 0;
        }
    } else {
        int idx = (bx - 9) * 256 + t;
        if (idx < NBUCKET * B_ * D_) gbuf[idx] = 0.f;
    }
}

__global__ __launch_bounds__(256) void k_main(
    const float* __restrict__ emb, const bf16x8* __restrict__ w7f,
    const float* __restrict__ w5, float* __restrict__ gbuf,
    float* __restrict__ qi, float* __restrict__ qj)
{
    __shared__ bf16x8 sB[2048];   // 32 KB, fragment-order: idx = tt*256 + s*64 + lane

    const int t = threadIdx.x, b = blockIdx.y;
    {   // stage B (linear copy, coalesced, conflict-free)
        const uint4* src = (const uint4*)w7f;
        uint4* dst = (uint4*)sB;
        #pragma unroll
        for (int i = 0; i < 8; ++i) dst[t + 256 * i] = src[t + 256 * i];
    }
    __syncthreads();

    const int wv = t >> 6, lane = t & 63, rc = lane & 15, kg = lane >> 4;
    const int tile = blockIdx.x * 4 + wv;
    if (tile >= TILES_) return;   // no barriers after this point

    const float4* A4 = (const float4*)(emb + (size_t)b * N_ * D_);
    const int rowbase = tile * 32;

    f32x4 acc[2][8] = {};
    float ga[32];
    #pragma unroll
    for (int i = 0; i < 32; ++i) ga[i] = 0.f;

    #pragma unroll
    for (int s = 0; s < 4; ++s) {
        bf16x8 bfr[8];
        #pragma unroll
        for (int tt = 0; tt < 8; ++tt)
            bfr[tt] = sB[tt * 256 + s * 64 + lane];
        #pragma unroll
        for (int rt = 0; rt < 2; ++rt) {
            // A fragment direct from global: 32 contiguous bytes per lane,
            // kg=0..3 lanes tile a 128B line; 16 rc rows -> 16 full lines.
            const float4* p = A4 + (rowbase + rt * 16 + rc) * 32 + s * 8 + kg * 2;
            float4 a0 = p[0], a1 = p[1];
            ga[s*8+0] += a0.x; ga[s*8+1] += a0.y; ga[s*8+2] += a0.z; ga[s*8+3] += a0.w;
            ga[s*8+4] += a1.x; ga[s*8+5] += a1.y; ga[s*8+6] += a1.z; ga[s*8+7] += a1.w;
            union { bf16x8 v; __hip_bfloat16 h[8]; } pk;
            pk.h[0] = __float2bfloat16(a0.x); pk.h[1] = __float2bfloat16(a0.y);
            pk.h[2] = __float2bfloat16(a0.z); pk.h[3] = __float2bfloat16(a0.w);
            pk.h[4] = __float2bfloat16(a1.x); pk.h[5] = __float2bfloat16(a1.y);
            pk.h[6] = __float2bfloat16(a1.z); pk.h[7] = __float2bfloat16(a1.w);
            #pragma unroll
            for (int tt = 0; tt < 8; ++tt)
                acc[rt][tt] = __builtin_amdgcn_mfma_f32_16x16x32_bf16(pk.v, bfr[tt], acc[rt][tt], 0, 0, 0);
        }
    }

    // epilogue: leaky, dot w5_i/w5_j over cols, shfl-reduce over rc, store
    // D layout: col = rc (+16*tt), row = kg*4 + reg
    #pragma unroll
    for (int rt = 0; rt < 2; ++rt) {
        float qip[4] = {0,0,0,0}, qjp[4] = {0,0,0,0};
        #pragma unroll
        for (int tt = 0; tt < 8; ++tt) {
            int col = tt * 16 + rc;
            float wi = w5[D_ + col], wj = w5[2 * D_ + col];
            #pragma unroll
            for (int r = 0; r < 4; ++r) {
                float pv = acc[rt][tt][r];
                float lr = (pv >= 0.f) ? pv : 0.01f * pv;
                qip[r] += lr * wi; qjp[r] += lr * wj;
            }
        }
        #pragma unroll
        for (int m = 1; m < 16; m <<= 1) {
            #pragma unroll
            for (int r = 0; r < 4; ++r) {
                qip[r] += __shfl_xor(qip[r], m);
                qjp[r] += __shfl_xor(qjp[r], m);
            }
        }
        if (rc == 0) {
            #pragma unroll
            for (int r = 0; r < 4; ++r) {
                int node = rowbase + rt * 16 + kg * 4 + r;
                qi[b * N_ + node] = qip[r];
                qj[b * N_ + node] = qjp[r];
            }
        }
    }

    // g: reduce per-lane col partials over rc, bucketed atomics
    #pragma unroll
    for (int m = 1; m < 16; m <<= 1) {
        #pragma unroll
        for (int i = 0; i < 32; ++i) ga[i] += __shfl_xor(ga[i], m);
    }
    if (rc == 0) {
        float* gb = gbuf + (tile & (NBUCKET - 1)) * (B_ * D_) + b * D_;
        #pragma unroll
        for (int s = 0; s < 4; ++s) {
            #pragma unroll
            for (int m = 0; m < 8; ++m)
                atomicAdd(&gb[s * 32 + kg * 8 + m], ga[s * 8 + m]);
        }
    }
}

// fused: per-block redundant qg compute (cheap) + edge gather
__global__ __launch_bounds__(256) void k_edge(
    const int* __restrict__ edges, const int* __restrict__ flag,
    const float* __restrict__ gbuf, const float* __restrict__ W6,
    const float* __restrict__ w5, const float* __restrict__ wno,
    const float* __restrict__ qi, const float* __restrict__ qj,
    float* __restrict__ out)
{
    __shared__ float sg[B_][D_];
    __shared__ float sp2[2][B_][D_];
    __shared__ float sred[2][B_], sredn[2][B_];
    __shared__ float sqg[B_];

    const int t = threadIdx.x;
    const int e = t & 127, half = t >> 7;

    if (t < 128) {
        #pragma unroll
        for (int b = 0; b < B_; ++b) {
            float s = 0.f;
            #pragma unroll
            for (int k = 0; k < NBUCKET; ++k)
                s += gbuf[k * (B_ * D_) + b * D_ + e];
            sg[b][e] = s;
        }
    }
    __syncthreads();

    {   // partial matvec p[b][e] over d in [half*64, half*64+64)
        float p[B_] = {0,0,0,0};
        const int d0 = half * 64;
        for (int d = d0; d < d0 + 64; ++d) {
            float w6 = W6[d * D_ + e];
            #pragma unroll
            for (int b = 0; b < B_; ++b) p[b] += sg[b][d] * w6;
        }
        #pragma unroll
        for (int b = 0; b < B_; ++b) sp2[half][b][e] = p[b];
    }
    __syncthreads();

    if (t < 128) {
        float vq[B_], vn[B_];
        #pragma unroll
        for (int b = 0; b < B_; ++b) {
            float pv = sp2[0][b][e] + sp2[1][b][e];
            float lr = (pv >= 0.f) ? pv : 0.01f * pv;
            vq[b] = lr * w5[e];          // w5_g
            vn[b] = sg[b][e] * wno[e];   // noop
        }
        #pragma unroll
        for (int m = 1; m < 64; m <<= 1) {
            #pragma unroll
            for (int b = 0; b < B_; ++b) {
                vq[b] += __shfl_xor(vq[b], m);
                vn[b] += __shfl_xor(vn[b], m);
            }
        }
        if ((t & 63) == 0) {
            #pragma unroll
            for (int b = 0; b < B_; ++b) {
                sred[t >> 6][b] = vq[b];
                sredn[t >> 6][b] = vn[b];
            }
        }
    }
    __syncthreads();
    if (t == 0) {
        #pragma unroll
        for (int b = 0; b < B_; ++b) {
            sqg[b] = sred[0][b] + sred[1][b];
            if (blockIdx.x == 0)
                out[b * (size_t)(E_ + 1) + E_] = sredn[0][b] + sredn[1][b];
        }
    }
    __syncthreads();

    const int ei = blockIdx.x * 256 + t;
    if (ei < E_) {
        int u, v;
        if (*flag) { int4 w = ((const int4*)edges)[ei]; u = w.x; v = w.z; }
        else       { int2 w = ((const int2*)edges)[ei]; u = w.x; v = w.y; }
        #pragma unroll
        for (int b = 0; b < B_; ++b)
            out[b * (size_t)(E_ + 1) + ei] = sqg[b] + qi[b * N_ + u] + qj[b * N_ + v];
    }
}

extern "C" void kernel_launch(void* const* d_in, const int* in_sizes, int n_in,
                              void* d_out, int out_size, void* d_ws, size_t ws_size,
                              hipStream_t stream)
{
    const float* emb   = (const float*)d_in[0];
    const int*   edges = (const int*)d_in[1];
    const float* W6    = (const float*)d_in[2];
    const float* W7    = (const float*)d_in[3];
    const float* w5    = (const float*)d_in[4];
    const float* wno   = (const float*)d_in[5];
    float* out = (float*)d_out;

    float* W = (float*)d_ws;
    int*   flag = (int*)W;
    float* gbuf = W + 256;
    bf16x8* w7f = (bf16x8*)(W + 8448);
    float* qi = W + 16640;
    float* qj = W + 96640;

    hipLaunchKernelGGL(k_prep, dim3(41), dim3(256), 0, stream,
                       W7, (const unsigned*)edges, flag, gbuf, w7f);
    hipLaunchKernelGGL(k_main, dim3((TILES_ + 3) / 4, B_), dim3(256), 0, stream,
                       emb, w7f, w5, gbuf, qi, qj);
    hipLaunchKernelGGL(k_edge, dim3((E_ + 255) / 256), dim3(256), 0, stream,
                       edges, flag, gbuf, W6, w5, wno, qi, qj, out);
}